// Round 2
// baseline (378.864 us; speedup 1.0000x reference)
//
#include <hip/hip_runtime.h>

// BERT-CRF fused: (1) emission = log_softmax(embed @ W^T + b) over T=9,
//                 (2) CRF log-likelihood (numerator + 511-step forward scan).
//
// Shapes: B=64, S=512, E=1024, T=9.
// d_out layout: [0] = log_likelihood (fp32), [1 .. 1+B*S*T) = emission (B,S,T) fp32.
//
// Kernel A (emis_kernel): one wave per (b,s) row. k-loop over 4 chunks of 256
//   elements; lane covers 4 floats per chunk (64*4*4 = 1024 = E). W re-loaded
//   per chunk (L1/L2-resident, 36 KB total). 9 butterfly reductions,
//   in-register log_softmax. Memory-bound: 134 MB embed read -> ~21 us floor.
// Kernel B (crf_kernel): one wave per batch. Emission row-block (18 KB) staged
//   to LDS; numerator lane-parallel over s; forward scan with replicated
//   9-score vector in registers, lane j computes next score[j], broadcast via
//   __shfl (compile-time src lane -> v_readlane). atomicAdd of (num-den) into
//   d_out[0] (zeroed by kernel A block 0).

#define BB 64
#define SS 512
#define EE 1024
#define TT 9

__global__ __launch_bounds__(256) void emis_kernel(
    const float* __restrict__ embed,   // (B*S, E)
    const float* __restrict__ W,       // (T, E)
    const float* __restrict__ bias,    // (T)
    float* __restrict__ out)           // [0]=llh, [1..]=emission
{
    if (blockIdx.x == 0 && threadIdx.x == 0) out[0] = 0.0f;  // llh accumulator

    const int row  = (blockIdx.x * 256 + threadIdx.x) >> 6;  // global wave id
    const int lane = threadIdx.x & 63;

    float acc[TT];
#pragma unroll
    for (int t = 0; t < TT; ++t) acc[t] = 0.0f;

    // E=1024 = 4 chunks x (64 lanes x 4 floats)
#pragma unroll
    for (int k = 0; k < 4; ++k) {
        const int off = k * 256 + 4 * lane;
        const float4 x = *(const float4*)(embed + (size_t)row * EE + off);
#pragma unroll
        for (int t = 0; t < TT; ++t) {
            const float4 w = *(const float4*)(W + t * EE + off);
            acc[t] += x.x * w.x + x.y * w.y + x.z * w.z + x.w * w.w;
        }
    }

    // Wave reduction (butterfly) for each of the 9 dot products.
#pragma unroll
    for (int t = 0; t < TT; ++t) {
#pragma unroll
        for (int o = 32; o > 0; o >>= 1)
            acc[t] += __shfl_xor(acc[t], o, 64);
        acc[t] += bias[t];  // uniform scalar load
    }

    // log_softmax over T=9 (all lanes redundantly; registers only)
    float m = acc[0];
#pragma unroll
    for (int t = 1; t < TT; ++t) m = fmaxf(m, acc[t]);
    float ssum = 0.0f;
#pragma unroll
    for (int t = 0; t < TT; ++t) ssum += __expf(acc[t] - m);
    const float lse = m + __logf(ssum);

    // Select acc[lane] without dynamic register indexing, lanes 0..8 store.
    float val = acc[0];
#pragma unroll
    for (int t = 1; t < TT; ++t) val = (lane == t) ? acc[t] : val;
    if (lane < TT)
        out[1 + (size_t)row * TT + lane] = val - lse;
}

__global__ __launch_bounds__(64) void crf_kernel(
    const float* __restrict__ outbase,  // d_out ([0]=llh, emission at +1)
    const int* __restrict__ tags,       // (B,S) int32
    const int* __restrict__ mask,       // (B,S) int32
    const float* __restrict__ start_t,  // (T)
    const float* __restrict__ end_t,    // (T)
    const float* __restrict__ trans,    // (T,T)
    float* __restrict__ out)            // [0] accumulate llh
{
    __shared__ float em_s[SS * TT];  // 18 KB: this batch's emission rows

    const int b = blockIdx.x;
    const int lane = threadIdx.x;  // single wave per block
    const float* em = outbase + 1 + (size_t)b * SS * TT;

    // Stage emission into LDS.
    for (int i = lane; i < SS * TT; i += 64) em_s[i] = em[i];

    // ---- numerator: lane-parallel over s ----
    float num = 0.0f;
    int msum = 0;
    for (int s = lane; s < SS; s += 64) {
        const int mk = mask[b * SS + s];
        msum += mk;
        const int tg = tags[b * SS + s];
        if (s == 0) {
            num += start_t[tg] + em_s[tg];
        } else {
            const int tp = tags[b * SS + s - 1];
            num += (float)mk * (trans[tp * TT + tg] + em_s[s * TT + tg]);
        }
    }
#pragma unroll
    for (int o = 32; o > 0; o >>= 1) {
        num += __shfl_xor(num, o, 64);
        msum += __shfl_xor(msum, o, 64);
    }
    const int seq_last = msum - 1;
    num += end_t[tags[b * SS + seq_last]];

    // ---- denominator: forward scan ----
    const int j = (lane < TT) ? lane : 0;
    float tcol[TT];  // trans[:, j] for this lane's column
#pragma unroll
    for (int i = 0; i < TT; ++i) tcol[i] = trans[i * TT + j];

    float score[TT];  // replicated across lanes
#pragma unroll
    for (int i = 0; i < TT; ++i) score[i] = start_t[i] + em_s[i];

    // software prefetch one step ahead (LDS + mask out of the dependency chain)
    float em_j = em_s[TT + j];
    int mcur = mask[b * SS + 1];

    for (int s = 1; s < SS; ++s) {
        const int nidx = (s + 1 < SS) ? (s + 1) : (SS - 1);
        const float em_nx = em_s[nidx * TT + j];
        const int m_nx = mask[b * SS + nidx];

        float a[TT];
#pragma unroll
        for (int i = 0; i < TT; ++i) a[i] = score[i] + tcol[i];
        float mx = a[0];
#pragma unroll
        for (int i = 1; i < TT; ++i) mx = fmaxf(mx, a[i]);
        float sum = 0.0f;
#pragma unroll
        for (int i = 0; i < TT; ++i) sum += __expf(a[i] - mx);
        const float nxt = mx + __logf(sum) + em_j;

        // broadcast lanes 0..8 -> all lanes, masked update
#pragma unroll
        for (int i = 0; i < TT; ++i) {
            const float ni = __shfl(nxt, i, 64);
            score[i] = (mcur > 0) ? ni : score[i];
        }
        em_j = em_nx;
        mcur = m_nx;
    }

    // denominator = lse(score + end)
    float a2[TT];
#pragma unroll
    for (int i = 0; i < TT; ++i) a2[i] = score[i] + end_t[i];
    float mx2 = a2[0];
#pragma unroll
    for (int i = 1; i < TT; ++i) mx2 = fmaxf(mx2, a2[i]);
    float sum2 = 0.0f;
#pragma unroll
    for (int i = 0; i < TT; ++i) sum2 += __expf(a2[i] - mx2);
    const float den = mx2 + __logf(sum2);

    if (lane == 0) atomicAdd(out, num - den);
}

extern "C" void kernel_launch(void* const* d_in, const int* in_sizes, int n_in,
                              void* d_out, int out_size, void* d_ws, size_t ws_size,
                              hipStream_t stream) {
    const float* embed   = (const float*)d_in[0];
    const int*   tags    = (const int*)d_in[1];
    const int*   mask    = (const int*)d_in[2];
    const float* W       = (const float*)d_in[3];
    const float* bias    = (const float*)d_in[4];
    const float* start_t = (const float*)d_in[5];
    const float* end_t   = (const float*)d_in[6];
    const float* trans   = (const float*)d_in[7];
    float* out = (float*)d_out;

    // B*S = 32768 rows, one wave each -> 8192 blocks of 256 (4 waves)
    emis_kernel<<<8192, 256, 0, stream>>>(embed, W, bias, out);
    // one wave per batch
    crf_kernel<<<BB, 64, 0, stream>>>(out, tags, mask, start_t, end_t, trans, out);
}

// Round 3
// 252.515 us; speedup vs baseline: 1.5004x; 1.5004x over previous
//
#include <hip/hip_runtime.h>

// BERT-CRF fused. Shapes: B=64, S=512, E=1024, T=9.
// d_out: [0]=llh, [1 .. 1+B*S*T)=emission (B,S,T) fp32.
//
// emis_kernel: one wave per 4 rows; per 256-elem chunk load W frag once (36
//   VGPRs) and FMA 4 rows against it (W L1 traffic /4). Butterfly-reduce 9
//   dots, in-register log_softmax. HBM floor ~21 us (134 MB embed).
//
// CRF scan in LINEAR space: since em is log_softmax, exp(em) rows sum to 1,
// so transfer matrices M_s = exp(trans) o diag(exp(em_s)) have row sums
// ~e^{+-0.1}; products over 511 steps stay within e^{+-15} -> fp32-safe, no
// rescaling, no logsumexp in any dependency chain.
//   crf_chunk: 4096 waves (64 batches x 64 chunks of 8 steps). Lane i = row i
//     of the chunk's running 9x9 product; E=exp(trans) in 81 lane-uniform
//     VGPRs; 8 x (81 FMA + 9 mul); masked steps = identity (skip). Writes
//     chunk matrices to d_ws (needs 4096*81*4 = 1.33 MB).
//   crf_final: 64 blocks x 256: numerator (lane-parallel gather) + LDS tree
//     reduction of 64 chunk mats (depth 6, append-buffer, no in-place race),
//     den = log(v0^T Mtot e^end), atomicAdd(num-den) into out[0] (zeroed by
//     emis block 0 each call).

#define BB 64
#define SS 512
#define EE 1024
#define TT 9

__global__ __launch_bounds__(256) void emis_kernel(
    const float* __restrict__ embed,   // (B*S, E)
    const float* __restrict__ W,       // (T, E)
    const float* __restrict__ bias,    // (T)
    float* __restrict__ out)           // [0]=llh, [1..]=emission
{
    if (blockIdx.x == 0 && threadIdx.x == 0) out[0] = 0.0f;  // llh accumulator

    const int wid  = threadIdx.x >> 6;
    const int lane = threadIdx.x & 63;
    const int row0 = blockIdx.x * 16 + wid * 4;  // 4 rows per wave

    float acc[4][TT];
#pragma unroll
    for (int r = 0; r < 4; ++r)
#pragma unroll
        for (int t = 0; t < TT; ++t) acc[r][t] = 0.0f;

    // E=1024 = 4 chunks x (64 lanes x 4 floats); W frag reused across 4 rows
#pragma unroll
    for (int k = 0; k < 4; ++k) {
        const int off = k * 256 + 4 * lane;
        float4 w[TT];
#pragma unroll
        for (int t = 0; t < TT; ++t)
            w[t] = *(const float4*)(W + t * EE + off);
#pragma unroll
        for (int r = 0; r < 4; ++r) {
            const float4 x = *(const float4*)(embed + (size_t)(row0 + r) * EE + off);
#pragma unroll
            for (int t = 0; t < TT; ++t)
                acc[r][t] += x.x * w[t].x + x.y * w[t].y + x.z * w[t].z + x.w * w[t].w;
        }
    }

#pragma unroll
    for (int r = 0; r < 4; ++r) {
#pragma unroll
        for (int t = 0; t < TT; ++t) {
#pragma unroll
            for (int o = 32; o > 0; o >>= 1)
                acc[r][t] += __shfl_xor(acc[r][t], o, 64);
            acc[r][t] += bias[t];
        }
        float m = acc[r][0];
#pragma unroll
        for (int t = 1; t < TT; ++t) m = fmaxf(m, acc[r][t]);
        float ssum = 0.0f;
#pragma unroll
        for (int t = 0; t < TT; ++t) ssum += __expf(acc[r][t] - m);
        const float lse = m + __logf(ssum);

        float val = acc[r][0];
#pragma unroll
        for (int t = 1; t < TT; ++t) val = (lane == t) ? acc[r][t] : val;
        if (lane < TT)
            out[1 + (size_t)(row0 + r) * TT + lane] = val - lse;
    }
}

// ---- CRF stage 1: per-chunk linear-space matrix products ----
__global__ __launch_bounds__(256) void crf_chunk(
    const float* __restrict__ outbase,  // d_out ([0]=llh, em at +1)
    const int* __restrict__ mask,       // (B,S)
    const float* __restrict__ trans,    // (T,T)
    float* __restrict__ ws)             // (B*64) matrices of 81 floats
{
    const int gw   = (blockIdx.x * 256 + threadIdx.x) >> 6;  // 0..4095
    const int lane = threadIdx.x & 63;
    const int b = gw >> 6;        // batch
    const int c = gw & 63;        // chunk
    const int i = (lane < TT) ? lane : 0;  // row of chunk product

    const float* em = outbase + 1 + (size_t)b * SS * TT;

    // E = exp(trans): lane-uniform, 81 VGPRs
    float E[TT * TT];
#pragma unroll
    for (int e = 0; e < TT * TT; ++e) E[e] = __expf(trans[e]);

    // first step of this chunk: s0 = 8c+1
    const int s0 = 8 * c + 1;
    float R[TT];
    {
        float p[TT];
#pragma unroll
        for (int j = 0; j < TT; ++j) p[j] = __expf(em[s0 * TT + j]);
        const int mk = mask[b * SS + s0];
#pragma unroll
        for (int k = 0; k < TT; ++k)
            R[k] = mk ? (E[i * TT + k] * p[k]) : ((k == i) ? 1.0f : 0.0f);
    }
#pragma unroll
    for (int d = 1; d < 8; ++d) {
        const int s = s0 + d;
        const bool valid = (s < SS);          // chunk 63 has only 7 steps
        const int sc = valid ? s : (SS - 1);
        float p[TT];
#pragma unroll
        for (int j = 0; j < TT; ++j) p[j] = __expf(em[sc * TT + j]);
        const int mk = valid ? mask[b * SS + sc] : 0;  // invalid/masked -> identity

        float nR[TT];
#pragma unroll
        for (int j = 0; j < TT; ++j) {
            float a = 0.0f;
#pragma unroll
            for (int k = 0; k < TT; ++k) a += R[k] * E[k * TT + j];
            nR[j] = a * p[j];
        }
#pragma unroll
        for (int j = 0; j < TT; ++j) R[j] = mk ? nR[j] : R[j];
    }
    if (lane < TT) {
#pragma unroll
        for (int j = 0; j < TT; ++j)
            ws[(size_t)gw * 81 + i * TT + j] = R[j];
    }
}

// ---- CRF stage 2: per-batch tree reduction + numerator + llh ----
__global__ __launch_bounds__(256) void crf_final(
    const float* __restrict__ outbase,
    const int* __restrict__ tags,
    const int* __restrict__ mask,
    const float* __restrict__ start_t,
    const float* __restrict__ end_t,
    const float* __restrict__ trans,
    const float* __restrict__ ws,
    float* __restrict__ out)
{
    __shared__ float mats[127 * 81];   // 64 in + 32+16+8+4+2+1 level outputs
    __shared__ float red[4];
    __shared__ float redm[4];

    const int b = blockIdx.x;
    const int tid = threadIdx.x;
    const int lane = tid & 63, wid = tid >> 6;
    const float* em = outbase + 1 + (size_t)b * SS * TT;

    for (int idx = tid; idx < 64 * 81; idx += 256)
        mats[idx] = ws[(size_t)b * 64 * 81 + idx];

    // ---- numerator: threads cover s = tid, tid+256 ----
    float num = 0.0f;
    int msum = 0;
    for (int s = tid; s < SS; s += 256) {
        const int mk = mask[b * SS + s];
        msum += mk;
        const int tg = tags[b * SS + s];
        if (s == 0) {
            num += start_t[tg] + em[tg];
        } else {
            const int tp = tags[b * SS + s - 1];
            num += (float)mk * (trans[tp * TT + tg] + em[s * TT + tg]);
        }
    }
#pragma unroll
    for (int o = 32; o > 0; o >>= 1) {
        num += __shfl_xor(num, o, 64);
        msum += __shfl_xor(msum, o, 64);
    }
    if (lane == 0) { red[wid] = num; redm[wid] = (float)msum; }
    __syncthreads();

    // ---- tree reduction: levels n = 32,16,8,4,2,1, append-buffer ----
    int inOff = 0, outOff = 64;
    for (int n = 32; n >= 1; n >>= 1) {
        for (int c = wid; c < n; c += 4) {
            const float* A  = mats + (inOff + 2 * c) * 81;
            const float* Bm = mats + (inOff + 2 * c + 1) * 81;
            float* C = mats + (outOff + c) * 81;
            int e = lane;                       // entries 0..63
            int ii = e / 9, jj = e - ii * 9;
            float a = 0.0f;
#pragma unroll
            for (int k = 0; k < TT; ++k) a += A[ii * 9 + k] * Bm[k * 9 + jj];
            C[e] = a;
            if (lane < 17) {                    // entries 64..80
                e = 64 + lane; ii = e / 9; jj = e - ii * 9;
                float a2 = 0.0f;
#pragma unroll
                for (int k = 0; k < TT; ++k) a2 += A[ii * 9 + k] * Bm[k * 9 + jj];
                C[e] = a2;
            }
        }
        __syncthreads();
        inOff = outOff; outOff += n;
    }
    // Mtot at mats + 126*81

    if (wid == 0) {
        const float* Mt = mats + 126 * 81;
        float v0[TT];
#pragma unroll
        for (int i2 = 0; i2 < TT; ++i2) v0[i2] = __expf(start_t[i2] + em[i2]);
        const int j = (lane < TT) ? lane : 0;
        float cs = 0.0f;
#pragma unroll
        for (int i2 = 0; i2 < TT; ++i2) cs += v0[i2] * Mt[i2 * 9 + j];
        float val = cs * __expf(end_t[j]);
        if (lane >= TT) val = 0.0f;
        // sum lanes 0..8 (lanes 9..15 are zero) via width-16 butterfly
#pragma unroll
        for (int o = 8; o > 0; o >>= 1) val += __shfl_xor(val, o, 64);
        if (lane == 0) {
            const float den = __logf(val);
            float numT = red[0] + red[1] + red[2] + red[3];
            const int ms = (int)(redm[0] + redm[1] + redm[2] + redm[3]);
            numT += end_t[tags[b * SS + (ms - 1)]];
            atomicAdd(out, numT - den);
        }
    }
}

extern "C" void kernel_launch(void* const* d_in, const int* in_sizes, int n_in,
                              void* d_out, int out_size, void* d_ws, size_t ws_size,
                              hipStream_t stream) {
    const float* embed   = (const float*)d_in[0];
    const int*   tags    = (const int*)d_in[1];
    const int*   mask    = (const int*)d_in[2];
    const float* W       = (const float*)d_in[3];
    const float* bias    = (const float*)d_in[4];
    const float* start_t = (const float*)d_in[5];
    const float* end_t   = (const float*)d_in[6];
    const float* trans   = (const float*)d_in[7];
    float* out = (float*)d_out;
    float* ws  = (float*)d_ws;   // needs 4096*81*4 = 1.33 MB

    // 32768 rows / 16 rows per block
    emis_kernel<<<2048, 256, 0, stream>>>(embed, W, bias, out);
    // 4096 chunk-waves / 4 waves per block
    crf_chunk<<<1024, 256, 0, stream>>>(out, mask, trans, ws);
    // one block per batch
    crf_final<<<BB, 256, 0, stream>>>(out, tags, mask, start_t, end_t, trans, ws, out);
}